// Round 2
// baseline (809.331 us; speedup 1.0000x reference)
//
#include <hip/hip_runtime.h>
#include <hip/hip_bf16.h>
#include <math.h>

#define B_   4
#define T_   2048
#define C_   2048
#define NH_  16
#define HD_  128
#define KVD_ 1024

typedef __attribute__((ext_vector_type(4))) float f32x4;
typedef __attribute__((ext_vector_type(16))) float f32x16;
typedef __attribute__((ext_vector_type(8))) short bf16x8;
typedef __attribute__((ext_vector_type(4))) unsigned int u32x4;

__device__ __forceinline__ void async_copy16(const __hip_bfloat16* g, __hip_bfloat16* l) {
  __builtin_amdgcn_global_load_lds((const __attribute__((address_space(1))) void*)g,
                                   (__attribute__((address_space(3))) void*)l,
                                   16, 0, 0);
}

__device__ __forceinline__ float bf2f(__hip_bfloat16 h) { return __bfloat162float(h); }

// pack two f32 -> one dword of 2 bf16 (a in low half)
__device__ __forceinline__ unsigned int pkbf(float a, float b) {
  float2 f2; f2.x = a; f2.y = b;
  __hip_bfloat162 h2 = __float22bfloat162_rn(f2);
  return *reinterpret_cast<unsigned int*>(&h2);
}

// ---------------- f32 -> bf16 convert (x) ----------------
__global__ __launch_bounds__(256) void f32_to_bf16_k(const float* __restrict__ src,
                                                     __hip_bfloat16* __restrict__ dst, int n4) {
  int i = blockIdx.x * 256 + threadIdx.x;
  if (i >= n4) return;
  float4 f = ((const float4*)src)[i];
  __hip_bfloat16 o[4] = {__float2bfloat16(f.x), __float2bfloat16(f.y),
                         __float2bfloat16(f.z), __float2bfloat16(f.w)};
  *(uint2*)(dst + (size_t)i * 4) = *(uint2*)o;
}

// ---------------- transpose + convert: WT[n][k] = bf16(W[k][n]) ----------------
__global__ __launch_bounds__(256) void transpose_f32_bf16_k(const float* __restrict__ W,
                                                            __hip_bfloat16* __restrict__ WT,
                                                            int K, int N) {
  __shared__ float tile[32][33];
  int bx = blockIdx.x * 32;  // n
  int by = blockIdx.y * 32;  // k
  int tx = threadIdx.x, ty = threadIdx.y;
  for (int i = ty; i < 32; i += 8)
    tile[i][tx] = W[(size_t)(by + i) * N + (bx + tx)];
  __syncthreads();
  for (int i = ty; i < 32; i += 8)
    WT[(size_t)(bx + i) * K + (by + tx)] = __float2bfloat16(tile[tx][i]);
}

// ---------------- V transpose: Vt[b][g][d][perm(t)] = kv[b][t][512 + g*128 + d] --------
// perm swaps bits 2<->3 of t within each 16-group. PV then sums over the permuted kv
// axis with P supplied in the SAME permuted order -> O is exact, and each lane's PV
// A-frag needs only its OWN S^T accumulator values (no cross-lane exchange at all).
__global__ __launch_bounds__(256) void vtrans_k(const __hip_bfloat16* __restrict__ kv,
                                                __hip_bfloat16* __restrict__ vt) {
  __shared__ __hip_bfloat16 tile[32][33];
  int bg = blockIdx.z;            // b*4+g
  int d0 = blockIdx.y * 32;
  int t0 = blockIdx.x * 32;
  int tx = threadIdx.x, ty = threadIdx.y;
  int b = bg >> 2, g = bg & 3;
  const __hip_bfloat16* src = kv + (size_t)b * T_ * KVD_ + 512 + g * HD_;
  for (int i = ty; i < 32; i += 8)
    tile[i][tx] = src[(size_t)(t0 + i) * KVD_ + d0 + tx];
  __syncthreads();
  __hip_bfloat16* dst = vt + (size_t)bg * HD_ * T_;
  int txp = (tx & ~12) | ((tx & 4) << 1) | ((tx & 8) >> 1);  // swap bits 2,3
  for (int i = ty; i < 32; i += 8)
    dst[(size_t)(d0 + i) * T_ + t0 + txp] = tile[tx][i];
}

// ---------------- row l2norm (in place, bf16), scale folded via `extra` ----------------
template<int PER>
__global__ __launch_bounds__(256) void rownorm_k(__hip_bfloat16* __restrict__ buf,
                                                 int stride, float extra) {
  const int tid = threadIdx.x;
  __hip_bfloat16* p = buf + (size_t)blockIdx.x * stride;
  float v[PER];
  float ss = 0.f;
  #pragma unroll
  for (int e = 0; e < PER; ++e) { v[e] = bf2f(p[tid + e * 256]); ss += v[e] * v[e]; }
  #pragma unroll
  for (int off = 32; off >= 1; off >>= 1) ss += __shfl_xor(ss, off, 64);
  __shared__ float wsum[4];
  if ((tid & 63) == 0) wsum[tid >> 6] = ss;
  __syncthreads();
  float tot = wsum[0] + wsum[1] + wsum[2] + wsum[3];
  float sc = extra / (sqrtf(tot) + 1e-12f);
  #pragma unroll
  for (int e = 0; e < PER; ++e) p[tid + e * 256] = __float2bfloat16(v[e] * sc);
}

// ---------------- GEMM: C[M][N] = A[M][K] @ BT[N][K]^T, bf16 in, OutT out ----------------
template<typename OutT>
__global__ __launch_bounds__(256) void gemm_bt_k(const __hip_bfloat16* __restrict__ A,
                                                 const __hip_bfloat16* __restrict__ BT,
                                                 OutT* __restrict__ Cc,
                                                 int M, int N, int K) {
  __shared__ alignas(16) __hip_bfloat16 As[128 * 32];
  __shared__ alignas(16) __hip_bfloat16 Bs[128 * 32];
  const int tid = threadIdx.x;
  const int bm = blockIdx.y * 128;
  const int bn = blockIdx.x * 128;
  const int wave = tid >> 6, lane = tid & 63;
  const int wr = (wave >> 1) * 64, wc = (wave & 1) * 64;
  const int lm = lane & 15, lk = (lane >> 4) * 8;
  const size_t Kz = (size_t)K;
  const __hip_bfloat16* a0 = A + (size_t)(bm + (tid >> 2)) * Kz + (size_t)((tid & 3) * 8);
  const __hip_bfloat16* b0 = BT + (size_t)(bn + (tid >> 2)) * Kz + (size_t)((tid & 3) * 8);
  const __hip_bfloat16* a1 = a0 + 64 * Kz;
  const __hip_bfloat16* b1 = b0 + 64 * Kz;
  f32x4 acc[4][4] = {};
  for (int k0 = 0; k0 < K; k0 += 32) {
    async_copy16(a0 + k0, As + tid * 8);
    async_copy16(a1 + k0, As + 2048 + tid * 8);
    async_copy16(b0 + k0, Bs + tid * 8);
    async_copy16(b1 + k0, Bs + 2048 + tid * 8);
    __syncthreads();
    bf16x8 af[4], bfr[4];
    #pragma unroll
    for (int t = 0; t < 4; ++t) {
      af[t]  = *(const bf16x8*)(As + (wr + t * 16 + lm) * 32 + lk);
      bfr[t] = *(const bf16x8*)(Bs + (wc + t * 16 + lm) * 32 + lk);
    }
    #pragma unroll
    for (int mt = 0; mt < 4; ++mt)
      #pragma unroll
      for (int nt = 0; nt < 4; ++nt)
        acc[mt][nt] = __builtin_amdgcn_mfma_f32_16x16x32_bf16(af[mt], bfr[nt], acc[mt][nt], 0, 0, 0);
    __syncthreads();
  }
  const int r0 = (lane >> 4) * 4;
  #pragma unroll
  for (int mt = 0; mt < 4; ++mt)
    #pragma unroll
    for (int nt = 0; nt < 4; ++nt)
      #pragma unroll
      for (int r = 0; r < 4; ++r) {
        int gr = bm + wr + mt * 16 + r0 + r;
        int gc = bn + wc + nt * 16 + lm;
        float v = acc[mt][nt][r];
        if constexpr (__is_same(OutT, float))
          Cc[(size_t)gr * N + gc] = v;
        else
          Cc[(size_t)gr * N + gc] = __float2bfloat16(v);
      }
}

// ---------------- flash attention v5: triangle-folded, 8-wave blocks ----------------
// Each block handles the q-tile PAIR {7-p, p} (256 rows each, 8 waves x 32 rows):
// total K-tiles per block = (4(7-p)+4) + (4p+4) = 36 for every block -> perfectly
// uniform grid of 256 blocks, all co-resident (2 blocks/CU, 16 waves/CU = 4/SIMD).
// Per-wave compute identical to v4: swapped QK^T (32x32x16), P fully in-register via
// the bit-2/3-swapped V layout, bounded scores (no running max).
__global__ __launch_bounds__(512, 4) void attn_k(const __hip_bfloat16* __restrict__ q,
                                                 const __hip_bfloat16* __restrict__ kv,
                                                 const __hip_bfloat16* __restrict__ vt,
                                                 __hip_bfloat16* __restrict__ y) {
  const int pp = blockIdx.x;      // pair index 0..3
  const int h  = blockIdx.y;
  const int b  = blockIdx.z;
  const int g  = h >> 2;
  const int tid = threadIdx.x;
  const int wave = tid >> 6, lane = tid & 63;
  const int l31 = lane & 31, hi = lane >> 5;

  // XOR-swizzled tiles: K chunk (row,c) holds global chunk c^(row&15);
  // Vt chunk (row,c) holds global chunk c^(row&7). 16B chunks.
  __shared__ alignas(16) __hip_bfloat16 Ks[2][64 * 128];
  __shared__ alignas(16) __hip_bfloat16 Vts[2][128 * 64];

  const __hip_bfloat16* kb = kv + (size_t)b * T_ * KVD_ + g * HD_;
  const __hip_bfloat16* vb = vt + (size_t)(b * 4 + g) * HD_ * T_;

  auto stage = [&](int buf, int jt) {
    const size_t j1 = (size_t)jt * 64;
    #pragma unroll
    for (int e = 0; e < 2; ++e) {
      int idx = tid + e * 512;
      int row = idx >> 4, c = idx & 15;
      async_copy16(kb + (j1 + row) * KVD_ + ((c ^ (row & 15)) * 8), Ks[buf] + idx * 8);
    }
    #pragma unroll
    for (int e = 0; e < 2; ++e) {
      int idx = tid + e * 512;
      int row = idx >> 3, c = idx & 7;
      async_copy16(vb + (size_t)row * T_ + j1 + ((c ^ (row & 7)) * 8), Vts[buf] + idx * 8);
    }
  };

  stage(0, 0);  // first tile of first segment

  #pragma unroll
  for (int seg = 0; seg < 2; ++seg) {
    const int qt = seg ? pp : (7 - pp);          // heavy q-tile first
    const int qbase = qt * 256 + wave * 32;
    const int qmax = qbase + 31;
    const int ntiles = 4 * qt + 4;

    // Q -> registers (one row per lane&31; hi half picks the 8-elem sub-chunk)
    const __hip_bfloat16* qrow = q + ((size_t)b * T_ + qbase + l31) * C_ + h * HD_;
    bf16x8 qf[8];
    #pragma unroll
    for (int kc = 0; kc < 8; ++kc)
      qf[kc] = *(const bf16x8*)(qrow + kc * 16 + hi * 8);

    __syncthreads();  // tile 0 of this segment staged & buffers free

    f32x16 o_acc[4] = {};
    float l_acc = 0.f;

    for (int it = 0; it < ntiles; ++it) {
      const int cur = it & 1;
      if (it + 1 < ntiles) stage(cur ^ 1, it + 1);
      const int j0 = it * 64;
      if (j0 <= qmax) {  // wave-uniform: skip fully-masked tiles
        // ---- S^T = K Q^T : acc layout col=lane&31=q-row, row=kv-local ----
        f32x16 st0 = {}, st1 = {};
        __builtin_amdgcn_s_setprio(1);
        #pragma unroll
        for (int kc = 0; kc < 8; ++kc) {
          const int cs0 = (((2 * kc + hi) ^ (l31 & 15)) * 8);
          bf16x8 k0 = *(const bf16x8*)(Ks[cur] + l31 * 128 + cs0);
          bf16x8 k1 = *(const bf16x8*)(Ks[cur] + (32 + l31) * 128 + cs0);
          st0 = __builtin_amdgcn_mfma_f32_32x32x16_bf16(k0, qf[kc], st0, 0, 0, 0);
          st1 = __builtin_amdgcn_mfma_f32_32x32x16_bf16(k1, qf[kc], st1, 0, 0, 0);
        }
        __builtin_amdgcn_s_setprio(0);
        // ---- P = exp(S) + causal mask; per-lane only (q row = lane&31) ----
        const int qd = qbase + l31 - j0;  // kv_local <= qd is unmasked
        if (j0 + 63 <= qbase) {           // tile fully unmasked: skip compares
          #pragma unroll
          for (int r = 0; r < 16; ++r) {
            float p0 = __expf(st0[r]);
            float p1 = __expf(st1[r]);
            st0[r] = p0; st1[r] = p1;
            l_acc += p0 + p1;
          }
        } else {
          #pragma unroll
          for (int r = 0; r < 16; ++r) {
            const int ofs = (r & 3) + 8 * (r >> 2) + 4 * hi;  // kv_local (kt=0)
            float p0 = (ofs <= qd) ? __expf(st0[r]) : 0.f;
            float p1 = (ofs + 32 <= qd) ? __expf(st1[r]) : 0.f;
            st0[r] = p0; st1[r] = p1;
            l_acc += p0 + p1;
          }
        }
        // ---- pack P -> bf16 words W[m][i]; m = kv-group (8 kv), i = word ----
        unsigned int W[8][2];
        #pragma unroll
        for (int q4 = 0; q4 < 4; ++q4) {
          W[q4][0]     = pkbf(st0[4 * q4 + 0], st0[4 * q4 + 1]);
          W[q4][1]     = pkbf(st0[4 * q4 + 2], st0[4 * q4 + 3]);
          W[4 + q4][0] = pkbf(st1[4 * q4 + 0], st1[4 * q4 + 1]);
          W[4 + q4][1] = pkbf(st1[4 * q4 + 2], st1[4 * q4 + 3]);
        }
        // ---- O += P V (kv axis permuted identically in P-frag and V storage) ----
        __builtin_amdgcn_s_setprio(1);
        #pragma unroll
        for (int kc = 0; kc < 4; ++kc) {
          u32x4 pw;
          pw[0] = W[2 * kc][0]; pw[1] = W[2 * kc][1];
          pw[2] = W[2 * kc + 1][0]; pw[3] = W[2 * kc + 1][1];
          bf16x8 pf = __builtin_bit_cast(bf16x8, pw);
          const int csv = (((2 * kc + hi) ^ (l31 & 7)) * 8);
          #pragma unroll
          for (int ct = 0; ct < 4; ++ct) {
            bf16x8 vf = *(const bf16x8*)(Vts[cur] + (ct * 32 + l31) * 64 + csv);
            o_acc[ct] = __builtin_amdgcn_mfma_f32_32x32x16_bf16(pf, vf, o_acc[ct], 0, 0, 0);
          }
        }
        __builtin_amdgcn_s_setprio(0);
      }
      __syncthreads();  // drains prefetch vmcnt + protects buffer swap
    }

    // prefetch next segment's tile 0 (buffers idle after final sync above);
    // overlaps with the epilogue below. Next segment's top sync drains it.
    if (seg == 0) stage(0, 0);

    // ---- epilogue: finish row sums (other hi half), divide, store ----
    float lsum = l_acc + __shfl_xor(l_acc, 32, 64);
    __hip_bfloat16* yb = y + ((size_t)b * T_ + qbase) * C_ + h * HD_ + l31;
    #pragma unroll
    for (int ct = 0; ct < 4; ++ct)
      #pragma unroll
      for (int r = 0; r < 16; ++r) {
        int row = (r & 3) + 8 * (r >> 2) + 4 * hi;
        float linv = 1.0f / __shfl(lsum, row, 64);
        yb[(size_t)row * C_ + ct * 32] = __float2bfloat16(o_acc[ct][r] * linv);
      }
  }
}

extern "C" void kernel_launch(void* const* d_in, const int* in_sizes, int n_in,
                              void* d_out, int out_size, void* d_ws, size_t ws_size,
                              hipStream_t stream) {
  (void)in_sizes; (void)n_in; (void)out_size; (void)ws_size;
  const float* x     = (const float*)d_in[0];
  const float* Wq    = (const float*)d_in[1];
  const float* Wkv   = (const float*)d_in[2];
  const float* Wproj = (const float*)d_in[3];
  char* ws = (char*)d_ws;
  __hip_bfloat16* xb     = (__hip_bfloat16*)(ws);               // 32 MB (reused as y)
  __hip_bfloat16* WqT    = (__hip_bfloat16*)(ws + 33554432);    //  8 MB
  __hip_bfloat16* WkvT   = (__hip_bfloat16*)(ws + 41943040);    //  4 MB
  __hip_bfloat16* WprojT = (__hip_bfloat16*)(ws + 46137344);    //  8 MB
  __hip_bfloat16* qn     = (__hip_bfloat16*)(ws + 54525952);    // 32 MB
  __hip_bfloat16* kvb    = (__hip_bfloat16*)(ws + 88080384);    // 16 MB
  __hip_bfloat16* y      = xb;                                  // alias: xb dead after kv-gemm
  __hip_bfloat16* vt     = (__hip_bfloat16*)d_out;              // 16 MB scratch in d_out (dead before final gemm)
  float* out             = (float*)d_out;

  f32_to_bf16_k<<<16384, 256, 0, stream>>>(x, xb, 4194304);
  transpose_f32_bf16_k<<<dim3(64, 64), dim3(32, 8), 0, stream>>>(Wq, WqT, 2048, 2048);
  transpose_f32_bf16_k<<<dim3(32, 64), dim3(32, 8), 0, stream>>>(Wkv, WkvT, 2048, 1024);
  transpose_f32_bf16_k<<<dim3(64, 64), dim3(32, 8), 0, stream>>>(Wproj, WprojT, 2048, 2048);
  gemm_bt_k<__hip_bfloat16><<<dim3(16, 64), 256, 0, stream>>>(xb, WqT, qn, 8192, 2048, 2048);
  gemm_bt_k<__hip_bfloat16><<<dim3(8, 64), 256, 0, stream>>>(xb, WkvT, kvb, 8192, 1024, 2048);
  rownorm_k<8><<<8192, 256, 0, stream>>>(qn, 2048, 0.08838834764831845f);  // 1/sqrt(HD) folded
  rownorm_k<2><<<8192, 256, 0, stream>>>(kvb, 1024, 1.0f);
  vtrans_k<<<dim3(64, 4, 16), dim3(32, 8), 0, stream>>>(kvb, vt);
  attn_k<<<dim3(4, 16, 4), 512, 0, stream>>>(qn, kvb, vt, y);
  gemm_bt_k<float><<<dim3(16, 64), 256, 0, stream>>>(y, WprojT, out, 8192, 2048, 2048);
}

// Round 4
// 546.796 us; speedup vs baseline: 1.4801x; 1.4801x over previous
//
#include <hip/hip_runtime.h>
#include <hip/hip_bf16.h>
#include <math.h>

#define B_   4
#define T_   2048
#define C_   2048
#define NH_  16
#define HD_  128
#define KVD_ 1024

typedef __attribute__((ext_vector_type(4))) float f32x4;
typedef __attribute__((ext_vector_type(16))) float f32x16;
typedef __attribute__((ext_vector_type(8))) short bf16x8;
typedef __attribute__((ext_vector_type(4))) unsigned int u32x4;

__device__ __forceinline__ void async_copy16(const __hip_bfloat16* g, __hip_bfloat16* l) {
  __builtin_amdgcn_global_load_lds((const __attribute__((address_space(1))) void*)g,
                                   (__attribute__((address_space(3))) void*)l,
                                   16, 0, 0);
}

__device__ __forceinline__ float bf2f(__hip_bfloat16 h) { return __bfloat162float(h); }

// pack two f32 -> one dword of 2 bf16 (a in low half)
__device__ __forceinline__ unsigned int pkbf(float a, float b) {
  float2 f2; f2.x = a; f2.y = b;
  __hip_bfloat162 h2 = __float22bfloat162_rn(f2);
  return *reinterpret_cast<unsigned int*>(&h2);
}

// ---------------- f32 -> bf16 convert (x) ----------------
__global__ __launch_bounds__(256) void f32_to_bf16_k(const float* __restrict__ src,
                                                     __hip_bfloat16* __restrict__ dst, int n4) {
  int i = blockIdx.x * 256 + threadIdx.x;
  if (i >= n4) return;
  float4 f = ((const float4*)src)[i];
  __hip_bfloat16 o[4] = {__float2bfloat16(f.x), __float2bfloat16(f.y),
                         __float2bfloat16(f.z), __float2bfloat16(f.w)};
  *(uint2*)(dst + (size_t)i * 4) = *(uint2*)o;
}

// ---------------- transpose + convert: WT[n][k] = bf16(W[k][n]) ----------------
__global__ __launch_bounds__(256) void transpose_f32_bf16_k(const float* __restrict__ W,
                                                            __hip_bfloat16* __restrict__ WT,
                                                            int K, int N) {
  __shared__ float tile[32][33];
  int bx = blockIdx.x * 32;  // n
  int by = blockIdx.y * 32;  // k
  int tx = threadIdx.x, ty = threadIdx.y;
  for (int i = ty; i < 32; i += 8)
    tile[i][tx] = W[(size_t)(by + i) * N + (bx + tx)];
  __syncthreads();
  for (int i = ty; i < 32; i += 8)
    WT[(size_t)(bx + i) * K + (by + tx)] = __float2bfloat16(tile[tx][i]);
}

// ---------------- V transpose: Vt[b][g][d][perm(t)] = kv[b][t][512 + g*128 + d] --------
// perm swaps bits 2<->3 of t within each 16-group. PV then sums over the permuted kv
// axis with P supplied in the SAME permuted order -> O is exact, and each lane's PV
// A-frag needs only its OWN S^T accumulator values (no cross-lane exchange at all).
__global__ __launch_bounds__(256) void vtrans_k(const __hip_bfloat16* __restrict__ kv,
                                                __hip_bfloat16* __restrict__ vt) {
  __shared__ __hip_bfloat16 tile[32][33];
  int bg = blockIdx.z;            // b*4+g
  int d0 = blockIdx.y * 32;
  int t0 = blockIdx.x * 32;
  int tx = threadIdx.x, ty = threadIdx.y;
  int b = bg >> 2, g = bg & 3;
  const __hip_bfloat16* src = kv + (size_t)b * T_ * KVD_ + 512 + g * HD_;
  for (int i = ty; i < 32; i += 8)
    tile[i][tx] = src[(size_t)(t0 + i) * KVD_ + d0 + tx];
  __syncthreads();
  __hip_bfloat16* dst = vt + (size_t)bg * HD_ * T_;
  int txp = (tx & ~12) | ((tx & 4) << 1) | ((tx & 8) >> 1);  // swap bits 2,3
  for (int i = ty; i < 32; i += 8)
    dst[(size_t)(d0 + i) * T_ + t0 + txp] = tile[tx][i];
}

// ---------------- row l2norm (in place, bf16), scale folded via `extra` ----------------
template<int PER>
__global__ __launch_bounds__(256) void rownorm_k(__hip_bfloat16* __restrict__ buf,
                                                 int stride, float extra) {
  const int tid = threadIdx.x;
  __hip_bfloat16* p = buf + (size_t)blockIdx.x * stride;
  float v[PER];
  float ss = 0.f;
  #pragma unroll
  for (int e = 0; e < PER; ++e) { v[e] = bf2f(p[tid + e * 256]); ss += v[e] * v[e]; }
  #pragma unroll
  for (int off = 32; off >= 1; off >>= 1) ss += __shfl_xor(ss, off, 64);
  __shared__ float wsum[4];
  if ((tid & 63) == 0) wsum[tid >> 6] = ss;
  __syncthreads();
  float tot = wsum[0] + wsum[1] + wsum[2] + wsum[3];
  float sc = extra / (sqrtf(tot) + 1e-12f);
  #pragma unroll
  for (int e = 0; e < PER; ++e) p[tid + e * 256] = __float2bfloat16(v[e] * sc);
}

// ---------------- GEMM: C[M][N] = A[M][K] @ BT[N][K]^T, bf16 in, OutT out ----------------
template<typename OutT>
__global__ __launch_bounds__(256) void gemm_bt_k(const __hip_bfloat16* __restrict__ A,
                                                 const __hip_bfloat16* __restrict__ BT,
                                                 OutT* __restrict__ Cc,
                                                 int M, int N, int K) {
  __shared__ alignas(16) __hip_bfloat16 As[128 * 32];
  __shared__ alignas(16) __hip_bfloat16 Bs[128 * 32];
  const int tid = threadIdx.x;
  const int bm = blockIdx.y * 128;
  const int bn = blockIdx.x * 128;
  const int wave = tid >> 6, lane = tid & 63;
  const int wr = (wave >> 1) * 64, wc = (wave & 1) * 64;
  const int lm = lane & 15, lk = (lane >> 4) * 8;
  const size_t Kz = (size_t)K;
  const __hip_bfloat16* a0 = A + (size_t)(bm + (tid >> 2)) * Kz + (size_t)((tid & 3) * 8);
  const __hip_bfloat16* b0 = BT + (size_t)(bn + (tid >> 2)) * Kz + (size_t)((tid & 3) * 8);
  const __hip_bfloat16* a1 = a0 + 64 * Kz;
  const __hip_bfloat16* b1 = b0 + 64 * Kz;
  f32x4 acc[4][4] = {};
  for (int k0 = 0; k0 < K; k0 += 32) {
    async_copy16(a0 + k0, As + tid * 8);
    async_copy16(a1 + k0, As + 2048 + tid * 8);
    async_copy16(b0 + k0, Bs + tid * 8);
    async_copy16(b1 + k0, Bs + 2048 + tid * 8);
    __syncthreads();
    bf16x8 af[4], bfr[4];
    #pragma unroll
    for (int t = 0; t < 4; ++t) {
      af[t]  = *(const bf16x8*)(As + (wr + t * 16 + lm) * 32 + lk);
      bfr[t] = *(const bf16x8*)(Bs + (wc + t * 16 + lm) * 32 + lk);
    }
    #pragma unroll
    for (int mt = 0; mt < 4; ++mt)
      #pragma unroll
      for (int nt = 0; nt < 4; ++nt)
        acc[mt][nt] = __builtin_amdgcn_mfma_f32_16x16x32_bf16(af[mt], bfr[nt], acc[mt][nt], 0, 0, 0);
    __syncthreads();
  }
  const int r0 = (lane >> 4) * 4;
  #pragma unroll
  for (int mt = 0; mt < 4; ++mt)
    #pragma unroll
    for (int nt = 0; nt < 4; ++nt)
      #pragma unroll
      for (int r = 0; r < 4; ++r) {
        int gr = bm + wr + mt * 16 + r0 + r;
        int gc = bn + wc + nt * 16 + lm;
        float v = acc[mt][nt][r];
        if constexpr (__is_same(OutT, float))
          Cc[(size_t)gr * N + gc] = v;
        else
          Cc[(size_t)gr * N + gc] = __float2bfloat16(v);
      }
}

// ---------------- flash attention v6: triangle-folded at v4 geometry ----------------
// 256-thread blocks (4 waves x 32 q-rows, Q-tile 128) -- the proven 120-VGPR config.
// Each block processes the q-tile PAIR {15-p, p}: K-tile count = 2(15-p)+2 + 2p+2 = 36
// for EVERY block -> perfectly uniform grid of 512 blocks = exactly 2 resident per CU
// (LDS-limited), no load-imbalance tail. Per-wave compute identical to v4: swapped
// QK^T (32x32x16), P fully in-register via bit-2/3-swapped V layout, bounded scores.
__global__ __launch_bounds__(256, 2) void attn_k(const __hip_bfloat16* __restrict__ q,
                                                 const __hip_bfloat16* __restrict__ kv,
                                                 const __hip_bfloat16* __restrict__ vt,
                                                 __hip_bfloat16* __restrict__ y) {
  const int pp = blockIdx.x;      // pair index 0..7
  const int h  = blockIdx.y;
  const int b  = blockIdx.z;
  const int g  = h >> 2;
  const int tid = threadIdx.x;
  const int wave = tid >> 6, lane = tid & 63;
  const int l31 = lane & 31, hi = lane >> 5;

  // XOR-swizzled tiles: K chunk (row,c) holds global chunk c^(row&15);
  // Vt chunk (row,c) holds global chunk c^(row&7). 16B chunks.
  __shared__ alignas(16) __hip_bfloat16 Ks[2][64 * 128];
  __shared__ alignas(16) __hip_bfloat16 Vts[2][128 * 64];

  const __hip_bfloat16* kb = kv + (size_t)b * T_ * KVD_ + g * HD_;
  const __hip_bfloat16* vb = vt + (size_t)(b * 4 + g) * HD_ * T_;

  auto stage = [&](int buf, int jt) {
    const size_t j1 = (size_t)jt * 64;
    #pragma unroll
    for (int e = 0; e < 4; ++e) {
      int idx = tid + e * 256;
      int row = idx >> 4, c = idx & 15;
      async_copy16(kb + (j1 + row) * KVD_ + ((c ^ (row & 15)) * 8), Ks[buf] + idx * 8);
    }
    #pragma unroll
    for (int e = 0; e < 4; ++e) {
      int idx = tid + e * 256;
      int row = idx >> 3, c = idx & 7;
      async_copy16(vb + (size_t)row * T_ + j1 + ((c ^ (row & 7)) * 8), Vts[buf] + idx * 8);
    }
  };

  stage(0, 0);  // first tile of first segment

  #pragma unroll
  for (int seg = 0; seg < 2; ++seg) {
    const int qt = seg ? pp : (15 - pp);
    const int qbase = qt * 128 + wave * 32;
    const int qmax = qbase + 31;
    const int ntiles = 2 * qt + 2;

    // Q -> registers (one row per lane&31; hi half picks the 8-elem sub-chunk)
    const __hip_bfloat16* qrow = q + ((size_t)b * T_ + qbase + l31) * C_ + h * HD_;
    bf16x8 qf[8];
    #pragma unroll
    for (int kc = 0; kc < 8; ++kc)
      qf[kc] = *(const bf16x8*)(qrow + kc * 16 + hi * 8);

    __syncthreads();  // tile 0 of this segment staged (barrier drains vmcnt)

    f32x16 o_acc[4] = {};
    float l_acc = 0.f;

    for (int it = 0; it < ntiles; ++it) {
      const int cur = it & 1;
      if (it + 1 < ntiles) stage(cur ^ 1, it + 1);
      const int j0 = it * 64;
      if (j0 <= qmax) {  // wave-uniform: skip fully-masked tiles
        // ---- S^T = K Q^T : acc layout col=lane&31=q-row, row=kv-local ----
        f32x16 st0 = {}, st1 = {};
        __builtin_amdgcn_s_setprio(1);
        #pragma unroll
        for (int kc = 0; kc < 8; ++kc) {
          const int cs0 = (((2 * kc + hi) ^ (l31 & 15)) * 8);
          bf16x8 k0 = *(const bf16x8*)(Ks[cur] + l31 * 128 + cs0);
          bf16x8 k1 = *(const bf16x8*)(Ks[cur] + (32 + l31) * 128 + cs0);
          st0 = __builtin_amdgcn_mfma_f32_32x32x16_bf16(k0, qf[kc], st0, 0, 0, 0);
          st1 = __builtin_amdgcn_mfma_f32_32x32x16_bf16(k1, qf[kc], st1, 0, 0, 0);
        }
        __builtin_amdgcn_s_setprio(0);
        // ---- P = exp(S) + causal mask; per-lane only (q row = lane&31) ----
        const int qd = qbase + l31 - j0;  // kv_local <= qd is unmasked
        if (j0 + 63 <= qbase) {           // tile fully unmasked: skip compares
          #pragma unroll
          for (int r = 0; r < 16; ++r) {
            float p0 = __expf(st0[r]);
            float p1 = __expf(st1[r]);
            st0[r] = p0; st1[r] = p1;
            l_acc += p0 + p1;
          }
        } else {
          #pragma unroll
          for (int r = 0; r < 16; ++r) {
            const int ofs = (r & 3) + 8 * (r >> 2) + 4 * hi;  // kv_local (kt=0)
            float p0 = (ofs <= qd) ? __expf(st0[r]) : 0.f;
            float p1 = (ofs + 32 <= qd) ? __expf(st1[r]) : 0.f;
            st0[r] = p0; st1[r] = p1;
            l_acc += p0 + p1;
          }
        }
        // ---- pack P -> bf16 words W[m][i]; m = kv-group (8 kv), i = word ----
        unsigned int W[8][2];
        #pragma unroll
        for (int q4 = 0; q4 < 4; ++q4) {
          W[q4][0]     = pkbf(st0[4 * q4 + 0], st0[4 * q4 + 1]);
          W[q4][1]     = pkbf(st0[4 * q4 + 2], st0[4 * q4 + 3]);
          W[4 + q4][0] = pkbf(st1[4 * q4 + 0], st1[4 * q4 + 1]);
          W[4 + q4][1] = pkbf(st1[4 * q4 + 2], st1[4 * q4 + 3]);
        }
        // ---- O += P V (kv axis permuted identically in P-frag and V storage) ----
        __builtin_amdgcn_s_setprio(1);
        #pragma unroll
        for (int kc = 0; kc < 4; ++kc) {
          u32x4 pw;
          pw[0] = W[2 * kc][0]; pw[1] = W[2 * kc][1];
          pw[2] = W[2 * kc + 1][0]; pw[3] = W[2 * kc + 1][1];
          bf16x8 pf = __builtin_bit_cast(bf16x8, pw);
          const int csv = (((2 * kc + hi) ^ (l31 & 7)) * 8);
          #pragma unroll
          for (int ct = 0; ct < 4; ++ct) {
            bf16x8 vf = *(const bf16x8*)(Vts[cur] + (ct * 32 + l31) * 64 + csv);
            o_acc[ct] = __builtin_amdgcn_mfma_f32_32x32x16_bf16(pf, vf, o_acc[ct], 0, 0, 0);
          }
        }
        __builtin_amdgcn_s_setprio(0);
      }
      __syncthreads();  // drains prefetch vmcnt + protects buffer swap
    }

    // prefetch next segment's tile 0 (buffers idle after final sync above);
    // overlaps with the epilogue below. Next segment's top sync drains it.
    if (seg == 0) stage(0, 0);

    // ---- epilogue: finish row sums (other hi half), divide, store ----
    float lsum = l_acc + __shfl_xor(l_acc, 32, 64);
    float oinv[16];
    #pragma unroll
    for (int r = 0; r < 16; ++r) {
      int row = (r & 3) + 8 * (r >> 2) + 4 * hi;
      oinv[r] = 1.0f / __shfl(lsum, row, 64);
    }
    __hip_bfloat16* yb = y + ((size_t)b * T_ + qbase) * C_ + h * HD_ + l31;
    #pragma unroll
    for (int ct = 0; ct < 4; ++ct)
      #pragma unroll
      for (int r = 0; r < 16; ++r) {
        int row = (r & 3) + 8 * (r >> 2) + 4 * hi;
        yb[(size_t)row * C_ + ct * 32] = __float2bfloat16(o_acc[ct][r] * oinv[r]);
      }
  }
}

extern "C" void kernel_launch(void* const* d_in, const int* in_sizes, int n_in,
                              void* d_out, int out_size, void* d_ws, size_t ws_size,
                              hipStream_t stream) {
  (void)in_sizes; (void)n_in; (void)out_size; (void)ws_size;
  const float* x     = (const float*)d_in[0];
  const float* Wq    = (const float*)d_in[1];
  const float* Wkv   = (const float*)d_in[2];
  const float* Wproj = (const float*)d_in[3];
  char* ws = (char*)d_ws;
  __hip_bfloat16* xb     = (__hip_bfloat16*)(ws);               // 32 MB (reused as y)
  __hip_bfloat16* WqT    = (__hip_bfloat16*)(ws + 33554432);    //  8 MB
  __hip_bfloat16* WkvT   = (__hip_bfloat16*)(ws + 41943040);    //  4 MB
  __hip_bfloat16* WprojT = (__hip_bfloat16*)(ws + 46137344);    //  8 MB
  __hip_bfloat16* qn     = (__hip_bfloat16*)(ws + 54525952);    // 32 MB
  __hip_bfloat16* kvb    = (__hip_bfloat16*)(ws + 88080384);    // 16 MB
  __hip_bfloat16* y      = xb;                                  // alias: xb dead after kv-gemm
  __hip_bfloat16* vt     = (__hip_bfloat16*)d_out;              // 16 MB scratch in d_out (dead before final gemm)
  float* out             = (float*)d_out;

  f32_to_bf16_k<<<16384, 256, 0, stream>>>(x, xb, 4194304);
  transpose_f32_bf16_k<<<dim3(64, 64), dim3(32, 8), 0, stream>>>(Wq, WqT, 2048, 2048);
  transpose_f32_bf16_k<<<dim3(32, 64), dim3(32, 8), 0, stream>>>(Wkv, WkvT, 2048, 1024);
  transpose_f32_bf16_k<<<dim3(64, 64), dim3(32, 8), 0, stream>>>(Wproj, WprojT, 2048, 2048);
  gemm_bt_k<__hip_bfloat16><<<dim3(16, 64), 256, 0, stream>>>(xb, WqT, qn, 8192, 2048, 2048);
  gemm_bt_k<__hip_bfloat16><<<dim3(8, 64), 256, 0, stream>>>(xb, WkvT, kvb, 8192, 1024, 2048);
  rownorm_k<8><<<8192, 256, 0, stream>>>(qn, 2048, 0.08838834764831845f);  // 1/sqrt(HD) folded
  rownorm_k<2><<<8192, 256, 0, stream>>>(kvb, 1024, 1.0f);
  vtrans_k<<<dim3(64, 4, 16), dim3(32, 8), 0, stream>>>(kvb, vt);
  attn_k<<<dim3(8, 16, 4), 256, 0, stream>>>(qn, kvb, vt, y);
  gemm_bt_k<float><<<dim3(16, 64), 256, 0, stream>>>(y, WprojT, out, 8192, 2048, 2048);
}

// Round 5
// 466.928 us; speedup vs baseline: 1.7333x; 1.1711x over previous
//
#include <hip/hip_runtime.h>
#include <hip/hip_bf16.h>
#include <math.h>

#define B_   4
#define T_   2048
#define C_   2048
#define NH_  16
#define HD_  128
#define KVD_ 1024

typedef __attribute__((ext_vector_type(4))) float f32x4;
typedef __attribute__((ext_vector_type(16))) float f32x16;
typedef __attribute__((ext_vector_type(8))) short bf16x8;
typedef __attribute__((ext_vector_type(4))) unsigned int u32x4;

__device__ __forceinline__ void async_copy16(const __hip_bfloat16* g, __hip_bfloat16* l) {
  __builtin_amdgcn_global_load_lds((const __attribute__((address_space(1))) void*)g,
                                   (__attribute__((address_space(3))) void*)l,
                                   16, 0, 0);
}

__device__ __forceinline__ float bf2f(__hip_bfloat16 h) { return __bfloat162float(h); }

// pack two f32 -> one dword of 2 bf16 (a in low half)
__device__ __forceinline__ unsigned int pkbf(float a, float b) {
  float2 f2; f2.x = a; f2.y = b;
  __hip_bfloat162 h2 = __float22bfloat162_rn(f2);
  return *reinterpret_cast<unsigned int*>(&h2);
}

// ---------------- f32 -> bf16 convert (x) ----------------
__global__ __launch_bounds__(256) void f32_to_bf16_k(const float* __restrict__ src,
                                                     __hip_bfloat16* __restrict__ dst, int n4) {
  int i = blockIdx.x * 256 + threadIdx.x;
  if (i >= n4) return;
  float4 f = ((const float4*)src)[i];
  __hip_bfloat16 o[4] = {__float2bfloat16(f.x), __float2bfloat16(f.y),
                         __float2bfloat16(f.z), __float2bfloat16(f.w)};
  *(uint2*)(dst + (size_t)i * 4) = *(uint2*)o;
}

// ---------------- transpose + convert: WT[n][k] = bf16(W[k][n]) ----------------
__global__ __launch_bounds__(256) void transpose_f32_bf16_k(const float* __restrict__ W,
                                                            __hip_bfloat16* __restrict__ WT,
                                                            int K, int N) {
  __shared__ float tile[32][33];
  int bx = blockIdx.x * 32;  // n
  int by = blockIdx.y * 32;  // k
  int tx = threadIdx.x, ty = threadIdx.y;
  for (int i = ty; i < 32; i += 8)
    tile[i][tx] = W[(size_t)(by + i) * N + (bx + tx)];
  __syncthreads();
  for (int i = ty; i < 32; i += 8)
    WT[(size_t)(bx + i) * K + (by + tx)] = __float2bfloat16(tile[tx][i]);
}

// ---------------- V transpose: Vt[b][g][d][perm(t)] = kv[b][t][512 + g*128 + d] --------
// perm swaps bits 2<->3 of t within each 16-group (see attn_k P layout).
__global__ __launch_bounds__(256) void vtrans_k(const __hip_bfloat16* __restrict__ kv,
                                                __hip_bfloat16* __restrict__ vt) {
  __shared__ __hip_bfloat16 tile[32][33];
  int bg = blockIdx.z;            // b*4+g
  int d0 = blockIdx.y * 32;
  int t0 = blockIdx.x * 32;
  int tx = threadIdx.x, ty = threadIdx.y;
  int b = bg >> 2, g = bg & 3;
  const __hip_bfloat16* src = kv + (size_t)b * T_ * KVD_ + 512 + g * HD_;
  for (int i = ty; i < 32; i += 8)
    tile[i][tx] = src[(size_t)(t0 + i) * KVD_ + d0 + tx];
  __syncthreads();
  __hip_bfloat16* dst = vt + (size_t)bg * HD_ * T_;
  int txp = (tx & ~12) | ((tx & 4) << 1) | ((tx & 8) >> 1);  // swap bits 2,3
  for (int i = ty; i < 32; i += 8)
    dst[(size_t)(d0 + i) * T_ + t0 + txp] = tile[tx][i];
}

// ---------------- row l2norm (in place, bf16), scale folded via `extra` ----------------
template<int PER>
__global__ __launch_bounds__(256) void rownorm_k(__hip_bfloat16* __restrict__ buf,
                                                 int stride, float extra) {
  const int tid = threadIdx.x;
  __hip_bfloat16* p = buf + (size_t)blockIdx.x * stride;
  float v[PER];
  float ss = 0.f;
  #pragma unroll
  for (int e = 0; e < PER; ++e) { v[e] = bf2f(p[tid + e * 256]); ss += v[e] * v[e]; }
  #pragma unroll
  for (int off = 32; off >= 1; off >>= 1) ss += __shfl_xor(ss, off, 64);
  __shared__ float wsum[4];
  if ((tid & 63) == 0) wsum[tid >> 6] = ss;
  __syncthreads();
  float tot = wsum[0] + wsum[1] + wsum[2] + wsum[3];
  float sc = extra / (sqrtf(tot) + 1e-12f);
  #pragma unroll
  for (int e = 0; e < PER; ++e) p[tid + e * 256] = __float2bfloat16(v[e] * sc);
}

// ---------------- GEMM v2: ring-3 LDS, counted-vmcnt pipeline ----------------
// C[M][N] = A[M][K] @ BT[N][K]^T.  BM=128, BN=256, BK=64.  512 threads = 8 waves
// (2M x 4N), wave output 64x64 (acc 4x4 f32x4).  LDS: ring of 3 K-tiles
// (As[3] 16KB + Bs[3] 32KB = 144KB) -> compute slot t%3 while staging tile t+2
// into slot (t+2)%3 (freed by tile t-1, barrier-separated: no overwrite hazard).
// Full K-tile of landing slack -> per-tile wait is vmcnt(6) (6 loads/thread/tile
// in flight), NEVER a drain.  Raw s_barrier (no implicit vmcnt(0)).
// XOR chunk swizzle (c ^= row&7) on both stage-source and ds_read -> conflict-free.
template<typename OutT>
__global__ __launch_bounds__(512, 2) void gemm3_k(const __hip_bfloat16* __restrict__ A,
                                                  const __hip_bfloat16* __restrict__ BT,
                                                  OutT* __restrict__ Cc,
                                                  int M, int N, int K) {
  __shared__ alignas(16) __hip_bfloat16 As[3][128 * 64];
  __shared__ alignas(16) __hip_bfloat16 Bs[3][256 * 64];
  const int tid  = threadIdx.x;
  const int bm   = blockIdx.y * 128;
  const int bn   = blockIdx.x * 256;
  const int wave = tid >> 6, lane = tid & 63;
  const int wm = wave >> 2, wn = wave & 3;
  const int lm = lane & 15, quad = lane >> 4;
  const size_t Kz = (size_t)K;
  const int NT = K >> 6;

  // staging: thread's linear LDS slot idx*16B; source chunk pre-swizzled (c ^ row&7)
  const int srow = tid >> 3;                        // 0..63
  const int csw  = ((tid & 7) ^ (srow & 7)) * 8;    // element offset of swizzled 16B chunk
  const __hip_bfloat16* aSrc0 = A  + (size_t)(bm + srow) * Kz + csw;
  const __hip_bfloat16* aSrc1 = A  + (size_t)(bm + 64 + srow) * Kz + csw;
  const __hip_bfloat16* bSrc0 = BT + (size_t)(bn + srow) * Kz + csw;
  const __hip_bfloat16* bSrc1 = BT + (size_t)(bn + 64 + srow) * Kz + csw;
  const __hip_bfloat16* bSrc2 = BT + (size_t)(bn + 128 + srow) * Kz + csw;
  const __hip_bfloat16* bSrc3 = BT + (size_t)(bn + 192 + srow) * Kz + csw;

  auto stageA = [&](int slot, int koff) {
    async_copy16(aSrc0 + koff, As[slot] + tid * 8);
    async_copy16(aSrc1 + koff, As[slot] + (512 + tid) * 8);
  };
  auto stageB0 = [&](int slot, int koff) {
    async_copy16(bSrc0 + koff, Bs[slot] + tid * 8);
  };
  auto stageB123 = [&](int slot, int koff) {
    async_copy16(bSrc1 + koff, Bs[slot] + (512 + tid) * 8);
    async_copy16(bSrc2 + koff, Bs[slot] + (1024 + tid) * 8);
    async_copy16(bSrc3 + koff, Bs[slot] + (1536 + tid) * 8);
  };

  // ds_read chunk offsets (elements): chunk (kk*4+quad) ^ (row&7); row&7 == lm&7
  const int ch0 = ((quad) ^ (lm & 7)) * 8;
  const int ch1 = ((4 + quad) ^ (lm & 7)) * 8;
  const int arow = wm * 64 + lm;
  const int brow = wn * 64 + lm;

  f32x4 acc[4][4] = {};

  // prologue: stage tiles 0 and 1
  stageA(0, 0); stageB0(0, 0); stageB123(0, 0);
  if (NT > 1) { stageA(1, 64); stageB0(1, 64); stageB123(1, 64); }

  int s = 0;
  for (int t = 0; t < NT; ++t) {
    const int sn = (s + 2 > 2) ? (s - 1) : (s + 2);   // (s+2)%3
    const bool pre = (t + 2) < NT;
    const int koff = (t + 2) * 64;
    if (t + 1 < NT) asm volatile("s_waitcnt vmcnt(6)" ::: "memory");
    else            asm volatile("s_waitcnt vmcnt(0)" ::: "memory");
    __builtin_amdgcn_s_barrier();
    // ---- phase 0: all A-frags + B n-frags 0-1; MFMA left half ----
    bf16x8 af[4][2], bf0[2][2];
    #pragma unroll
    for (int mf = 0; mf < 4; ++mf) {
      af[mf][0] = *(const bf16x8*)(As[s] + (arow + mf * 16) * 64 + ch0);
      af[mf][1] = *(const bf16x8*)(As[s] + (arow + mf * 16) * 64 + ch1);
    }
    #pragma unroll
    for (int nf = 0; nf < 2; ++nf) {
      bf0[nf][0] = *(const bf16x8*)(Bs[s] + (brow + nf * 16) * 64 + ch0);
      bf0[nf][1] = *(const bf16x8*)(Bs[s] + (brow + nf * 16) * 64 + ch1);
    }
    if (pre) { stageA(sn, koff); stageB0(sn, koff); }
    __builtin_amdgcn_s_barrier();
    __builtin_amdgcn_s_setprio(1);
    #pragma unroll
    for (int mf = 0; mf < 4; ++mf)
      #pragma unroll
      for (int nf = 0; nf < 2; ++nf) {
        acc[mf][nf] = __builtin_amdgcn_mfma_f32_16x16x32_bf16(af[mf][0], bf0[nf][0], acc[mf][nf], 0, 0, 0);
        acc[mf][nf] = __builtin_amdgcn_mfma_f32_16x16x32_bf16(af[mf][1], bf0[nf][1], acc[mf][nf], 0, 0, 0);
      }
    __builtin_amdgcn_s_setprio(0);
    __builtin_amdgcn_s_barrier();
    // ---- phase 1: B n-frags 2-3; MFMA right half ----
    bf16x8 bf1[2][2];
    #pragma unroll
    for (int nf = 0; nf < 2; ++nf) {
      bf1[nf][0] = *(const bf16x8*)(Bs[s] + (brow + (nf + 2) * 16) * 64 + ch0);
      bf1[nf][1] = *(const bf16x8*)(Bs[s] + (brow + (nf + 2) * 16) * 64 + ch1);
    }
    if (pre) stageB123(sn, koff);
    __builtin_amdgcn_s_barrier();
    __builtin_amdgcn_s_setprio(1);
    #pragma unroll
    for (int mf = 0; mf < 4; ++mf)
      #pragma unroll
      for (int nf = 0; nf < 2; ++nf) {
        acc[mf][nf + 2] = __builtin_amdgcn_mfma_f32_16x16x32_bf16(af[mf][0], bf1[nf][0], acc[mf][nf + 2], 0, 0, 0);
        acc[mf][nf + 2] = __builtin_amdgcn_mfma_f32_16x16x32_bf16(af[mf][1], bf1[nf][1], acc[mf][nf + 2], 0, 0, 0);
      }
    __builtin_amdgcn_s_setprio(0);
    s = (s == 2) ? 0 : s + 1;
  }

  // epilogue (same mapping as proven kernel)
  const int r0 = quad * 4;
  #pragma unroll
  for (int mf = 0; mf < 4; ++mf)
    #pragma unroll
    for (int nf = 0; nf < 4; ++nf)
      #pragma unroll
      for (int r = 0; r < 4; ++r) {
        int gr = bm + wm * 64 + mf * 16 + r0 + r;
        int gc = bn + wn * 64 + nf * 16 + lm;
        float v = acc[mf][nf][r];
        if constexpr (__is_same(OutT, float))
          Cc[(size_t)gr * N + gc] = v;
        else
          Cc[(size_t)gr * N + gc] = __float2bfloat16(v);
      }
}

// ---------------- flash attention v6: triangle-folded (unchanged from R4) ----------------
__global__ __launch_bounds__(256, 2) void attn_k(const __hip_bfloat16* __restrict__ q,
                                                 const __hip_bfloat16* __restrict__ kv,
                                                 const __hip_bfloat16* __restrict__ vt,
                                                 __hip_bfloat16* __restrict__ y) {
  const int pp = blockIdx.x;      // pair index 0..7
  const int h  = blockIdx.y;
  const int b  = blockIdx.z;
  const int g  = h >> 2;
  const int tid = threadIdx.x;
  const int wave = tid >> 6, lane = tid & 63;
  const int l31 = lane & 31, hi = lane >> 5;

  __shared__ alignas(16) __hip_bfloat16 Ks[2][64 * 128];
  __shared__ alignas(16) __hip_bfloat16 Vts[2][128 * 64];

  const __hip_bfloat16* kb = kv + (size_t)b * T_ * KVD_ + g * HD_;
  const __hip_bfloat16* vb = vt + (size_t)(b * 4 + g) * HD_ * T_;

  auto stage = [&](int buf, int jt) {
    const size_t j1 = (size_t)jt * 64;
    #pragma unroll
    for (int e = 0; e < 4; ++e) {
      int idx = tid + e * 256;
      int row = idx >> 4, c = idx & 15;
      async_copy16(kb + (j1 + row) * KVD_ + ((c ^ (row & 15)) * 8), Ks[buf] + idx * 8);
    }
    #pragma unroll
    for (int e = 0; e < 4; ++e) {
      int idx = tid + e * 256;
      int row = idx >> 3, c = idx & 7;
      async_copy16(vb + (size_t)row * T_ + j1 + ((c ^ (row & 7)) * 8), Vts[buf] + idx * 8);
    }
  };

  stage(0, 0);  // first tile of first segment

  #pragma unroll
  for (int seg = 0; seg < 2; ++seg) {
    const int qt = seg ? pp : (15 - pp);
    const int qbase = qt * 128 + wave * 32;
    const int qmax = qbase + 31;
    const int ntiles = 2 * qt + 2;

    const __hip_bfloat16* qrow = q + ((size_t)b * T_ + qbase + l31) * C_ + h * HD_;
    bf16x8 qf[8];
    #pragma unroll
    for (int kc = 0; kc < 8; ++kc)
      qf[kc] = *(const bf16x8*)(qrow + kc * 16 + hi * 8);

    __syncthreads();  // tile 0 of this segment staged (barrier drains vmcnt)

    f32x16 o_acc[4] = {};
    float l_acc = 0.f;

    for (int it = 0; it < ntiles; ++it) {
      const int cur = it & 1;
      if (it + 1 < ntiles) stage(cur ^ 1, it + 1);
      const int j0 = it * 64;
      if (j0 <= qmax) {
        f32x16 st0 = {}, st1 = {};
        __builtin_amdgcn_s_setprio(1);
        #pragma unroll
        for (int kc = 0; kc < 8; ++kc) {
          const int cs0 = (((2 * kc + hi) ^ (l31 & 15)) * 8);
          bf16x8 k0 = *(const bf16x8*)(Ks[cur] + l31 * 128 + cs0);
          bf16x8 k1 = *(const bf16x8*)(Ks[cur] + (32 + l31) * 128 + cs0);
          st0 = __builtin_amdgcn_mfma_f32_32x32x16_bf16(k0, qf[kc], st0, 0, 0, 0);
          st1 = __builtin_amdgcn_mfma_f32_32x32x16_bf16(k1, qf[kc], st1, 0, 0, 0);
        }
        __builtin_amdgcn_s_setprio(0);
        const int qd = qbase + l31 - j0;
        if (j0 + 63 <= qbase) {
          #pragma unroll
          for (int r = 0; r < 16; ++r) {
            float p0 = __expf(st0[r]);
            float p1 = __expf(st1[r]);
            st0[r] = p0; st1[r] = p1;
            l_acc += p0 + p1;
          }
        } else {
          #pragma unroll
          for (int r = 0; r < 16; ++r) {
            const int ofs = (r & 3) + 8 * (r >> 2) + 4 * hi;
            float p0 = (ofs <= qd) ? __expf(st0[r]) : 0.f;
            float p1 = (ofs + 32 <= qd) ? __expf(st1[r]) : 0.f;
            st0[r] = p0; st1[r] = p1;
            l_acc += p0 + p1;
          }
        }
        unsigned int W[8][2];
        #pragma unroll
        for (int q4 = 0; q4 < 4; ++q4) {
          W[q4][0]     = pkbf(st0[4 * q4 + 0], st0[4 * q4 + 1]);
          W[q4][1]     = pkbf(st0[4 * q4 + 2], st0[4 * q4 + 3]);
          W[4 + q4][0] = pkbf(st1[4 * q4 + 0], st1[4 * q4 + 1]);
          W[4 + q4][1] = pkbf(st1[4 * q4 + 2], st1[4 * q4 + 3]);
        }
        __builtin_amdgcn_s_setprio(1);
        #pragma unroll
        for (int kc = 0; kc < 4; ++kc) {
          u32x4 pw;
          pw[0] = W[2 * kc][0]; pw[1] = W[2 * kc][1];
          pw[2] = W[2 * kc + 1][0]; pw[3] = W[2 * kc + 1][1];
          bf16x8 pf = __builtin_bit_cast(bf16x8, pw);
          const int csv = (((2 * kc + hi) ^ (l31 & 7)) * 8);
          #pragma unroll
          for (int ct = 0; ct < 4; ++ct) {
            bf16x8 vf = *(const bf16x8*)(Vts[cur] + (ct * 32 + l31) * 64 + csv);
            o_acc[ct] = __builtin_amdgcn_mfma_f32_32x32x16_bf16(pf, vf, o_acc[ct], 0, 0, 0);
          }
        }
        __builtin_amdgcn_s_setprio(0);
      }
      __syncthreads();
    }

    if (seg == 0) stage(0, 0);

    float lsum = l_acc + __shfl_xor(l_acc, 32, 64);
    float oinv[16];
    #pragma unroll
    for (int r = 0; r < 16; ++r) {
      int row = (r & 3) + 8 * (r >> 2) + 4 * hi;
      oinv[r] = 1.0f / __shfl(lsum, row, 64);
    }
    __hip_bfloat16* yb = y + ((size_t)b * T_ + qbase) * C_ + h * HD_ + l31;
    #pragma unroll
    for (int ct = 0; ct < 4; ++ct)
      #pragma unroll
      for (int r = 0; r < 16; ++r) {
        int row = (r & 3) + 8 * (r >> 2) + 4 * hi;
        yb[(size_t)row * C_ + ct * 32] = __float2bfloat16(o_acc[ct][r] * oinv[r]);
      }
  }
}

extern "C" void kernel_launch(void* const* d_in, const int* in_sizes, int n_in,
                              void* d_out, int out_size, void* d_ws, size_t ws_size,
                              hipStream_t stream) {
  (void)in_sizes; (void)n_in; (void)out_size; (void)ws_size;
  const float* x     = (const float*)d_in[0];
  const float* Wq    = (const float*)d_in[1];
  const float* Wkv   = (const float*)d_in[2];
  const float* Wproj = (const float*)d_in[3];
  char* ws = (char*)d_ws;
  __hip_bfloat16* xb     = (__hip_bfloat16*)(ws);               // 32 MB (reused as y)
  __hip_bfloat16* WqT    = (__hip_bfloat16*)(ws + 33554432);    //  8 MB
  __hip_bfloat16* WkvT   = (__hip_bfloat16*)(ws + 41943040);    //  4 MB
  __hip_bfloat16* WprojT = (__hip_bfloat16*)(ws + 46137344);    //  8 MB
  __hip_bfloat16* qn     = (__hip_bfloat16*)(ws + 54525952);    // 32 MB
  __hip_bfloat16* kvb    = (__hip_bfloat16*)(ws + 88080384);    // 16 MB
  __hip_bfloat16* y      = xb;                                  // alias: xb dead after kv-gemm
  __hip_bfloat16* vt     = (__hip_bfloat16*)d_out;              // 16 MB scratch in d_out
  float* out             = (float*)d_out;

  f32_to_bf16_k<<<16384, 256, 0, stream>>>(x, xb, 4194304);
  transpose_f32_bf16_k<<<dim3(64, 64), dim3(32, 8), 0, stream>>>(Wq, WqT, 2048, 2048);
  transpose_f32_bf16_k<<<dim3(32, 64), dim3(32, 8), 0, stream>>>(Wkv, WkvT, 2048, 1024);
  transpose_f32_bf16_k<<<dim3(64, 64), dim3(32, 8), 0, stream>>>(Wproj, WprojT, 2048, 2048);
  gemm3_k<__hip_bfloat16><<<dim3(8, 64), 512, 0, stream>>>(xb, WqT, qn, 8192, 2048, 2048);
  gemm3_k<__hip_bfloat16><<<dim3(4, 64), 512, 0, stream>>>(xb, WkvT, kvb, 8192, 1024, 2048);
  rownorm_k<8><<<8192, 256, 0, stream>>>(qn, 2048, 0.08838834764831845f);  // 1/sqrt(HD) folded
  rownorm_k<2><<<8192, 256, 0, stream>>>(kvb, 1024, 1.0f);
  vtrans_k<<<dim3(64, 4, 16), dim3(32, 8), 0, stream>>>(kvb, vt);
  attn_k<<<dim3(8, 16, 4), 256, 0, stream>>>(qn, kvb, vt, y);
  gemm3_k<float><<<dim3(8, 64), 512, 0, stream>>>(y, WprojT, out, 8192, 2048, 2048);
}